// Round 15
// baseline (621.053 us; speedup 1.0000x reference)
//
#include <hip/hip_runtime.h>
#include <hip/hip_bf16.h>

typedef __attribute__((ext_vector_type(4))) float float4v;
typedef __attribute__((ext_vector_type(8))) __bf16 bf16x8;
typedef __attribute__((ext_vector_type(8))) unsigned short ushort8v;

constexpr int NTOK = 50176;
constexpr int DIM  = 384;
constexpr int HID  = 1536;
constexpr int BM   = 64;          // tokens/block
constexpr int NTH  = 512;         // 8 waves
constexpr int NBLK = NTOK / BM;   // 784
constexpr int CHW  = 32;          // hidden chunk width
constexpr int NCH  = HID / CHW;   // 48

// workspace (byte offsets) — image formats IDENTICAL to R12/R14 (proven)
constexpr int IMG_WD  = 0;                      // W1-type [32 f][384 d], 768B rows, swz ^(f&7)<<4
constexpr int IMG_WUP = 24576;                  // linear  [384 d][32 c]
constexpr int IMG_W1  = 49152;                  // 48 x W1-type
constexpr int IMG_W2  = 49152 + 48 * 24576;     // 48 x linear [384 d][32 k]
constexpr size_t WS_NEED = 2408448;
constexpr int NELEMS = 1204224;

// LDS: W1 double-buffer (2x24K) + Hs (4K) = 52KB; 1 block/CU (reg-limited at (512,2))
constexpr int L_HS = 49152;
constexpr int LDSZ = 53248;

__device__ __forceinline__ unsigned short f2bf(float f) {
  __hip_bfloat16 h = __float2bfloat16(f);
  return *reinterpret_cast<unsigned short*>(&h);
}

__device__ __forceinline__ float gelu_f(float v) {
  float u = 0.7978845608f * (v + 0.044715f * v * v * v);
  float e = __expf(2.0f * u);
  float t = 1.0f - 2.0f / (e + 1.0f);
  return 0.5f * v * (1.0f + t);
}

// group-tiled byte address for [rows][32 cols] bf16: row r, 16B k-slot s
__device__ __forceinline__ int gt_addr(int r, int s) {
  return ((r >> 3) << 9) + (s << 7) + ((r & 7) << 4);
}

// 24KB stage, 512 threads, T14 split: load right after a barrier, write one phase later
__device__ __forceinline__ void st_load(const char* src, int tid, ushort8v st[3]) {
  #pragma unroll
  for (int j = 0; j < 3; ++j)
    st[j] = *(const ushort8v*)(src + tid * 16 + j * 8192);
}
__device__ __forceinline__ void st_wr(char* dst, int tid, const ushort8v st[3]) {
  #pragma unroll
  for (int j = 0; j < 3; ++j)
    *(ushort8v*)(dst + tid * 16 + j * 8192) = st[j];
}

// ---------------- pack kernel (identical to R12) ----------------
__global__ __launch_bounds__(256) void pack_k(
    const float* __restrict__ W1, const float* __restrict__ W2,
    const float* __restrict__ wd, const float* __restrict__ wu,
    unsigned short* __restrict__ img)
{
  int i = blockIdx.x * 256 + threadIdx.x;
  if (i >= NELEMS) return;
  if (i < 12288) {                               // WD (W1-type): [32 f][384 d] swz
    int f = i / 384; int inb = (i % 384) * 2;
    int d = (inb ^ ((f & 7) << 4)) >> 1;
    float v = (f < 24) ? wd[(f >> 3) * (DIM * 8) + d * 8 + (f & 7)] : 0.f;
    img[i] = f2bf(v);
  } else if (i < 24576) {                        // WUP linear [384 d][32 c]
    int j = i - 12288;
    int d = j / 32, c = j % 32;
    float v = (c < 24) ? wu[c * DIM + d] : 0.f;
    img[i] = f2bf(v);
  } else if (i < 24576 + 48 * 12288) {           // W1 chunks (W1-type swz)
    int j = i - 24576; int h = j / 12288; int jc = j % 12288;
    int f = jc / 384; int inb = (jc % 384) * 2;
    int d = (inb ^ ((f & 7) << 4)) >> 1;
    img[i] = f2bf(W1[d * HID + h * CHW + f]);
  } else {                                       // W2 chunks linear [384 d][32 k]
    int j = i - 24576 - 48 * 12288; int h = j / 12288; int jc = j % 12288;
    int d = jc / 32, k = jc % 32;
    img[i] = f2bf(W2[(h * CHW + k) * DIM + d]);
  }
}

// ---------------- fused MLP + MoE-LoRA ----------------
__global__ __launch_bounds__(NTH, 2) void fused_k(
    const float* __restrict__ x,
    const float* __restrict__ tp,
    const int*   __restrict__ ti,
    const float* __restrict__ b1,
    const float* __restrict__ b2,
    const unsigned short* __restrict__ img,
    float* __restrict__ out)
{
  extern __shared__ char lds[];
  const int tid = threadIdx.x, wid = tid >> 6, lane = tid & 63;
  const int lrow = lane & 15, g4 = lane >> 4;
  const int blockRow = blockIdx.x * BM;
  const char* imgc = (const char*)img;

  const int band = wid >> 1, chh = wid & 1;      // G1 grid: 4 bands x 2 col-halves
  const int wr = wid >> 2, wc = wid & 3;         // G2 grid: 2M x 4N

  ushort8v stg[3];                               // 12 regs, T14 staging

  // ---- prologue: issue WD; X f32->bf16 -> lds[0..48K) (temp, swizzled rows) ----
  st_load(imgc + IMG_WD, tid, stg);
  {
    const float* xb = x + (size_t)blockRow * DIM;
    #pragma unroll
    for (int it = 0; it < 6; ++it) {
      int idx = it * NTH + tid;
      int row = idx / 48, c8 = idx % 48;
      float4v v0 = *(const float4v*)(xb + row * DIM + c8 * 8);
      float4v v1 = *(const float4v*)(xb + row * DIM + c8 * 8 + 4);
      ushort8v u;
      u[0]=f2bf(v0[0]); u[1]=f2bf(v0[1]); u[2]=f2bf(v0[2]); u[3]=f2bf(v0[3]);
      u[4]=f2bf(v1[0]); u[5]=f2bf(v1[1]); u[6]=f2bf(v1[2]); u[7]=f2bf(v1[3]);
      int byte = (row * 768 + c8 * 16) ^ ((row & 7) << 4);
      *(ushort8v*)(lds + byte) = u;
    }
  }
  __syncthreads();                               // bar1: X visible

  // ---- xf: wave's 12 chunk-invariant A-frags -> registers (48 VGPRs) ----
  bf16x8 xf[12];
  {
    int raX = band * 16 + lrow;
    int sA = (raX & 7) << 4, baX = raX * 768 + g4 * 16;
    #pragma unroll
    for (int ks = 0; ks < 12; ++ks)
      xf[ks] = *(const bf16x8*)(lds + ((baX + ks * 64) ^ sA));
  }
  __syncthreads();                               // bar2: X reads done; lds free; WD landed

  st_wr(lds, tid, stg);                          // WD -> buf0
  st_load(imgc + IMG_W1, tid, stg);              // W1[0]; lands under G1-moe
  __syncthreads();                               // bar3: WD visible

  // ---- G1-moe: t1 = X @ WdT -> [64][32]; prob*gelu -> Hs ----
  {
    float4v hv = {};
    int rbW = chh * 16 + lrow;
    int sB = (rbW & 7) << 4, baW = rbW * 768 + g4 * 16;
    #pragma unroll
    for (int ks = 0; ks < 12; ++ks) {
      bf16x8 b = *(const bf16x8*)(lds + ((baW + ks * 64) ^ sB));
      hv = __builtin_amdgcn_mfma_f32_16x16x32_bf16(xf[ks], b, hv, 0, 0, 0);
    }
    int colc = chh * 16 + lrow; int e = colc >> 3;
    #pragma unroll
    for (int r = 0; r < 4; ++r) {
      int row = band * 16 + g4 * 4 + r;
      int token = blockRow + row;
      float p = 0.f;
      if (e < 3) {
        int i0 = ti[token * 2], i1 = ti[token * 2 + 1];
        if (i0 == e) p += tp[token * 2];
        if (i1 == e) p += tp[token * 2 + 1];
      }
      float gv = p * gelu_f(hv[r]);
      *(unsigned short*)(lds + L_HS + gt_addr(row, colc >> 3) + ((colc & 7) << 1)) = f2bf(gv);
    }
  }
  __syncthreads();                               // bar4: Hs visible; buf0 readers done; W1[0] landed
  st_wr(lds + 24576, tid, stg);                  // W1[0] -> buf1

  // ---- G2-moe: acc = Hs @ WupT (K=32); B direct from global WUP ----
  float4v acc[2][6] = {};
  {
    bf16x8 A[2];
    #pragma unroll
    for (int mt = 0; mt < 2; ++mt) {
      int ra = wr * 32 + mt * 16 + lrow;
      A[mt] = *(const bf16x8*)(lds + L_HS + gt_addr(ra, g4));
    }
    #pragma unroll
    for (int nt = 0; nt < 6; ++nt) {
      int rd = wc * 96 + nt * 16 + lrow;
      bf16x8 bfr = *(const bf16x8*)(imgc + IMG_WUP + rd * 64 + g4 * 16);
      acc[0][nt] = __builtin_amdgcn_mfma_f32_16x16x32_bf16(A[0], bfr, acc[0][nt], 0, 0, 0);
      acc[1][nt] = __builtin_amdgcn_mfma_f32_16x16x32_bf16(A[1], bfr, acc[1][nt], 0, 0, 0);
    }
  }

  // ---- main loop: 48 chunks, 2 barriers/chunk; W1[h] in buf[(h+1)&1] ----
  for (int h = 0; h < NCH; ++h) {
    __syncthreads();                             // bA: W1[h] visible; Hs readers (G2[h-1]) done
    if (h < NCH - 1)
      st_load(imgc + IMG_W1 + (h + 1) * 24576, tid, stg);   // lands under G1
    const char* bufR = lds + 24576 * ((h + 1) & 1);

    // G1: [64 tok][32 f] = X @ W1c; A from xf regs, B from LDS
    float4v hv = {};
    {
      int rbW = chh * 16 + lrow;
      int sB = (rbW & 7) << 4, baW = rbW * 768 + g4 * 16;
      #pragma unroll
      for (int ks = 0; ks < 12; ++ks) {
        bf16x8 b = *(const bf16x8*)(bufR + ((baW + ks * 64) ^ sB));
        hv = __builtin_amdgcn_mfma_f32_16x16x32_bf16(xf[ks], b, hv, 0, 0, 0);
      }
    }
    // bias + gelu -> Hs
    {
      int colc = chh * 16 + lrow;
      float bb = b1[h * CHW + colc];
      #pragma unroll
      for (int r = 0; r < 4; ++r) {
        int row = band * 16 + g4 * 4 + r;
        float gv = gelu_f(hv[r] + bb);
        *(unsigned short*)(lds + L_HS + gt_addr(row, colc >> 3) + ((colc & 7) << 1)) = f2bf(gv);
      }
    }
    __syncthreads();                             // bB: Hs visible; G1 done with bufR
    if (h < NCH - 1)
      st_wr(lds + 24576 * (h & 1), tid, stg);    // W1[h+1] into buffer freed by G1[h-1]

    // G2: acc += Hs @ W2c (K=32); A from Hs, B direct from global (L2-hot)
    {
      const char* w2b = imgc + IMG_W2 + h * 24576;
      bf16x8 A[2];
      #pragma unroll
      for (int mt = 0; mt < 2; ++mt) {
        int ra = wr * 32 + mt * 16 + lrow;
        A[mt] = *(const bf16x8*)(lds + L_HS + gt_addr(ra, g4));
      }
      #pragma unroll
      for (int nt = 0; nt < 6; ++nt) {
        int rd = wc * 96 + nt * 16 + lrow;
        bf16x8 bfr = *(const bf16x8*)(w2b + rd * 64 + g4 * 16);
        acc[0][nt] = __builtin_amdgcn_mfma_f32_16x16x32_bf16(A[0], bfr, acc[0][nt], 0, 0, 0);
        acc[1][nt] = __builtin_amdgcn_mfma_f32_16x16x32_bf16(A[1], bfr, acc[1][nt], 0, 0, 0);
      }
    }
  }

  // ---- epilogue: + b2, store f32 ----
  #pragma unroll
  for (int nt = 0; nt < 6; ++nt) {
    int col = wc * 96 + nt * 16 + lrow;
    float bb = b2[col];
    #pragma unroll
    for (int mt = 0; mt < 2; ++mt) {
      #pragma unroll
      for (int r = 0; r < 4; ++r) {
        int row = wr * 32 + mt * 16 + g4 * 4 + r;
        out[(size_t)(blockRow + row) * DIM + col] = acc[mt][nt][r] + bb;
      }
    }
  }
}

extern "C" void kernel_launch(void* const* d_in, const int* in_sizes, int n_in,
                              void* d_out, int out_size, void* d_ws, size_t ws_size,
                              hipStream_t stream) {
  const float* x          = (const float*)d_in[0];
  const float* topk_probs = (const float*)d_in[2];
  const int*   topk_idx   = (const int*)  d_in[3];
  const float* w_down     = (const float*)d_in[4];
  const float* w_up       = (const float*)d_in[5];
  const float* W1         = (const float*)d_in[6];
  const float* b1         = (const float*)d_in[7];
  const float* W2         = (const float*)d_in[8];
  const float* b2         = (const float*)d_in[9];
  float* out = (float*)d_out;

  if (ws_size < WS_NEED) return;

  hipFuncSetAttribute(reinterpret_cast<const void*>(fused_k),
                      hipFuncAttributeMaxDynamicSharedMemorySize, LDSZ);

  unsigned short* img = (unsigned short*)d_ws;
  pack_k<<<(NELEMS + 255) / 256, 256, 0, stream>>>(W1, W2, w_down, w_up, img);
  fused_k<<<NBLK, NTH, LDSZ, stream>>>(x, topk_probs, topk_idx, b1, b2, img, out);
}

// Round 16
// 459.805 us; speedup vs baseline: 1.3507x; 1.3507x over previous
//
#include <hip/hip_runtime.h>
#include <hip/hip_bf16.h>

typedef __attribute__((ext_vector_type(4)))  float float4v;
typedef __attribute__((ext_vector_type(16))) float float16v;
typedef __attribute__((ext_vector_type(8)))  __bf16 bf16x8;
typedef __attribute__((ext_vector_type(4)))  unsigned short ushort4v;
typedef __attribute__((ext_vector_type(8)))  unsigned short ushort8v;

constexpr int NTOK = 50176;
constexpr int DIM  = 384;
constexpr int HID  = 1536;
constexpr int BM   = 128;         // tokens/block
constexpr int NTH  = 512;         // 8 waves
constexpr int NBLK = NTOK / BM;   // 392
constexpr int CHW  = 64;          // hidden chunk width
constexpr int NCH  = HID / CHW;   // 24

// workspace (byte offsets), bf16 images:
// W1-type [rows f][384 d]: 768B rows, pre-swizzled ^(f&7)<<4  (LDS-staged)
// W2-type [384 d][K k]: plain linear (B-frags direct from global/L2)
constexpr int IMG_WD  = 0;                      // [32 c][384 d] swz
constexpr int IMG_WUP = 24576;                  // [384 d][32 c] linear, 64B rows
constexpr int IMG_W1  = 49152;                  // 24 x [64 f][384 d] swz, 49152B each
constexpr int IMG_W2  = 49152 + 24 * 49152;     // 24 x [384 d][64 k] linear, 128B rows
constexpr size_t WS_NEED = 2408448;
constexpr int NELEMS = 1204224;

// LDS = exactly 160 KiB, 1 block/CU
constexpr int L_X  = 0;        // 96K  X [128 tok][384 d], 768B rows, swz (r&7)<<4
constexpr int L_W  = 98304;    // 48K  W1 chunk [64 f][384 d], swz rows
constexpr int L_HS = 147456;   // 16K  Hs [128 tok][64 f], 128B rows, swz (tok&7)<<4
constexpr int LDSZ = 163840;

__device__ __forceinline__ unsigned short f2bf(float f) {
  __hip_bfloat16 h = __float2bfloat16(f);
  return *reinterpret_cast<unsigned short*>(&h);
}

__device__ __forceinline__ float gelu_f(float v) {
  float u = 0.7978845608f * (v + 0.044715f * v * v * v);
  float e = __expf(2.0f * u);
  float t = 1.0f - 2.0f / (e + 1.0f);
  return 0.5f * v * (1.0f + t);
}

// ---------------- pack kernel ----------------
__global__ __launch_bounds__(256) void pack_k(
    const float* __restrict__ W1, const float* __restrict__ W2,
    const float* __restrict__ wd, const float* __restrict__ wu,
    unsigned short* __restrict__ img)
{
  int i = blockIdx.x * 256 + threadIdx.x;
  if (i >= NELEMS) return;
  if (i < 12288) {                               // WD swz: [32 c][384 d]
    int f = i / 384; int inb = (i % 384) * 2;
    int d = (inb ^ ((f & 7) << 4)) >> 1;
    float v = (f < 24) ? wd[(f >> 3) * (DIM * 8) + d * 8 + (f & 7)] : 0.f;
    img[i] = f2bf(v);
  } else if (i < 24576) {                        // WUP linear [384 d][32 c]
    int j = i - 12288;
    int d = j / 32, c = j % 32;
    float v = (c < 24) ? wu[c * DIM + d] : 0.f;
    img[i] = f2bf(v);
  } else if (i < 24576 + 589824) {               // W1 chunks swz: 24 x [64 f][384 d]
    int j = i - 24576; int h = j / 24576; int jc = j % 24576;
    int f = jc / 384; int inb = (jc % 384) * 2;
    int d = (inb ^ ((f & 7) << 4)) >> 1;
    img[i] = f2bf(W1[d * HID + h * CHW + f]);
  } else {                                       // W2 chunks linear: 24 x [384 d][64 k]
    int j = i - 24576 - 589824; int h = j / 24576; int jc = j % 24576;
    int d = jc / 64, k = jc % 64;
    img[i] = f2bf(W2[(h * CHW + k) * DIM + d]);
  }
}

// ---------------- fused MLP + MoE-LoRA (32x32x16 MFMA) ----------------
__global__ __launch_bounds__(NTH, 2) void fused_k(
    const float* __restrict__ x,
    const float* __restrict__ tp,
    const int*   __restrict__ ti,
    const float* __restrict__ b1,
    const float* __restrict__ b2,
    const unsigned short* __restrict__ img,
    float* __restrict__ out)
{
  extern __shared__ char lds[];
  const int tid = threadIdx.x, wid = tid >> 6, lane = tid & 63;
  const int l31 = lane & 31, hi = lane >> 5;
  const int blockRow = blockIdx.x * BM;
  const char* imgc = (const char*)img;
  const int swz = (l31 & 7) << 4;

  const int fi = wid >> 2, tj = wid & 3;         // G1 grid: 2 f-tiles x 4 tok-tiles
  const int m  = wid >> 1, nh = wid & 1;         // G2 grid: 4 m-tiles x 2 n-halves

  ushort8v stg[6];                               // 24 regs; T14 staging

  // ---- prologue: WD loads; X f32->bf16 -> L_X (swizzled 768B rows) ----
  #pragma unroll
  for (int j = 0; j < 3; ++j)
    stg[j] = *(const ushort8v*)(imgc + IMG_WD + tid * 16 + j * 8192);
  {
    const float* xb = x + (size_t)blockRow * DIM;
    #pragma unroll
    for (int it = 0; it < 12; ++it) {
      int idx = it * NTH + tid;
      int row = idx / 48, c8 = idx % 48;
      float4v v0 = *(const float4v*)(xb + row * DIM + c8 * 8);
      float4v v1 = *(const float4v*)(xb + row * DIM + c8 * 8 + 4);
      ushort8v u;
      u[0]=f2bf(v0[0]); u[1]=f2bf(v0[1]); u[2]=f2bf(v0[2]); u[3]=f2bf(v0[3]);
      u[4]=f2bf(v1[0]); u[5]=f2bf(v1[1]); u[6]=f2bf(v1[2]); u[7]=f2bf(v1[3]);
      int byte = (row * 768 + c8 * 16) ^ ((row & 7) << 4);
      *(ushort8v*)(lds + L_X + byte) = u;
    }
  }
  __syncthreads();                               // bar1: X visible; WD regs landed
  #pragma unroll
  for (int j = 0; j < 3; ++j)
    *(ushort8v*)(lds + L_W + tid * 16 + j * 8192) = stg[j];
  #pragma unroll
  for (int j = 0; j < 6; ++j)
    stg[j] = *(const ushort8v*)(imgc + IMG_W1 + tid * 16 + j * 8192);  // W1[0]
  __syncthreads();                               // bar2: WD visible

  // ---- moe-G1 (fi==0 waves): t1^T[32 c][128 tok] = WD (x) X ----
  if (fi == 0) {
    float16v hv = {};
    #pragma unroll
    for (int kk = 0; kk < 24; ++kk) {
      bf16x8 a = *(const bf16x8*)(lds + L_W + ((l31 * 768 + kk * 32 + hi * 16) ^ swz));
      bf16x8 b = *(const bf16x8*)(lds + L_X + (((tj * 32 + l31) * 768 + kk * 32 + hi * 16) ^ swz));
      hv = __builtin_amdgcn_mfma_f32_32x32x16_bf16(a, b, hv, 0, 0, 0);
    }
    int tokl = tj * 32 + l31;
    int token = blockRow + tokl;
    int i0 = ti[token * 2], i1 = ti[token * 2 + 1];
    float p0 = tp[token * 2], p1 = tp[token * 2 + 1];
    int tswz = (tokl & 7) << 4;
    #pragma unroll
    for (int g = 0; g < 4; ++g) {                // e == g for this thread's c-run
      float pg = 0.f;
      if (g < 3) {
        if (i0 == g) pg += p0;
        if (i1 == g) pg += p1;
      }
      int fb = 8 * g + 4 * hi;
      ushort4v u;
      #pragma unroll
      for (int r = 0; r < 4; ++r) u[r] = f2bf(pg * gelu_f(hv[4 * g + r]));
      *(ushort4v*)(lds + L_HS + ((tokl * 128 + fb * 2) ^ tswz)) = u;
    }
  }
  __syncthreads();                               // bar3: Hs(moe) visible; WD readers done; W1[0] landed
  #pragma unroll
  for (int j = 0; j < 6; ++j)
    *(ushort8v*)(lds + L_W + tid * 16 + j * 8192) = stg[j];   // W1[0] -> L_W

  // ---- moe-G2: acc = t1 @ WupT (K=32); B direct from WUP ----
  float16v acc[6] = {};
  {
    bf16x8 af[2];
    #pragma unroll
    for (int kk = 0; kk < 2; ++kk)
      af[kk] = *(const bf16x8*)(lds + L_HS + (((m * 32 + l31) * 128 + kk * 32 + hi * 16) ^ swz));
    #pragma unroll
    for (int j = 0; j < 6; ++j) {
      int n = nh * 6 + j;
      #pragma unroll
      for (int kk = 0; kk < 2; ++kk) {
        bf16x8 bfr = *(const bf16x8*)(imgc + IMG_WUP + (n * 32 + l31) * 64 + kk * 32 + hi * 16);
        acc[j] = __builtin_amdgcn_mfma_f32_32x32x16_bf16(af[kk], bfr, acc[j], 0, 0, 0);
      }
    }
  }

  // ---- main loop: 24 chunks of 64 hidden; 2 barriers/chunk ----
  for (int h = 0; h < NCH; ++h) {
    __syncthreads();                             // bar A: W1[h] visible; Hs readers done
    if (h < NCH - 1) {
      #pragma unroll
      for (int j = 0; j < 6; ++j)
        stg[j] = *(const ushort8v*)(imgc + IMG_W1 + (h + 1) * 49152 + tid * 16 + j * 8192);
    }

    // G1: H^T[64 f][128 tok] = W1c (x) X ; one 32x32 tile per wave
    float16v hv = {};
    {
      int arow = (fi * 32 + l31) * 768;
      int brow = (tj * 32 + l31) * 768;
      #pragma unroll
      for (int kk = 0; kk < 24; ++kk) {
        bf16x8 a = *(const bf16x8*)(lds + L_W + ((arow + kk * 32 + hi * 16) ^ swz));
        bf16x8 b = *(const bf16x8*)(lds + L_X + ((brow + kk * 32 + hi * 16) ^ swz));
        hv = __builtin_amdgcn_mfma_f32_32x32x16_bf16(a, b, hv, 0, 0, 0);
      }
    }
    // bias + gelu -> Hs (b64 writes, f-contiguous runs)
    {
      int tokl = tj * 32 + l31;
      int tswz = (tokl & 7) << 4;
      #pragma unroll
      for (int g = 0; g < 4; ++g) {
        int fb = fi * 32 + 8 * g + 4 * hi;
        float4v bb = *(const float4v*)(b1 + h * 64 + fb);
        ushort4v u;
        #pragma unroll
        for (int r = 0; r < 4; ++r) u[r] = f2bf(gelu_f(hv[4 * g + r] + bb[r]));
        *(ushort4v*)(lds + L_HS + ((tokl * 128 + fb * 2) ^ tswz)) = u;
      }
    }
    __syncthreads();                             // bar B: Hs visible; G1's L_W reads done
    if (h < NCH - 1) {
      #pragma unroll
      for (int j = 0; j < 6; ++j)
        *(ushort8v*)(lds + L_W + tid * 16 + j * 8192) = stg[j];  // W1[h+1]
    }

    // G2: acc += H @ W2c (K=64); A-frags cached, B direct from global (L2-hot)
    {
      bf16x8 af[4];
      #pragma unroll
      for (int kk = 0; kk < 4; ++kk)
        af[kk] = *(const bf16x8*)(lds + L_HS + (((m * 32 + l31) * 128 + kk * 32 + hi * 16) ^ swz));
      const char* w2b = imgc + IMG_W2 + h * 49152;
      #pragma unroll
      for (int j = 0; j < 6; ++j) {
        int n = nh * 6 + j;
        #pragma unroll
        for (int kk = 0; kk < 4; ++kk) {
          bf16x8 bfr = *(const bf16x8*)(w2b + (n * 32 + l31) * 128 + kk * 32 + hi * 16);
          acc[j] = __builtin_amdgcn_mfma_f32_32x32x16_bf16(af[kk], bfr, acc[j], 0, 0, 0);
        }
      }
    }
  }

  // ---- epilogue: + b2, store f32 ----
  #pragma unroll
  for (int j = 0; j < 6; ++j) {
    int n = nh * 6 + j;
    int d = n * 32 + l31;
    float bb = b2[d];
    #pragma unroll
    for (int r = 0; r < 16; ++r) {
      int row = m * 32 + (r & 3) + 8 * (r >> 2) + 4 * hi;
      out[(size_t)(blockRow + row) * DIM + d] = acc[j][r] + bb;
    }
  }
}

extern "C" void kernel_launch(void* const* d_in, const int* in_sizes, int n_in,
                              void* d_out, int out_size, void* d_ws, size_t ws_size,
                              hipStream_t stream) {
  const float* x          = (const float*)d_in[0];
  const float* topk_probs = (const float*)d_in[2];
  const int*   topk_idx   = (const int*)  d_in[3];
  const float* w_down     = (const float*)d_in[4];
  const float* w_up       = (const float*)d_in[5];
  const float* W1         = (const float*)d_in[6];
  const float* b1         = (const float*)d_in[7];
  const float* W2         = (const float*)d_in[8];
  const float* b2         = (const float*)d_in[9];
  float* out = (float*)d_out;

  if (ws_size < WS_NEED) return;

  hipFuncSetAttribute(reinterpret_cast<const void*>(fused_k),
                      hipFuncAttributeMaxDynamicSharedMemorySize, LDSZ);

  unsigned short* img = (unsigned short*)d_ws;
  pack_k<<<(NELEMS + 255) / 256, 256, 0, stream>>>(W1, W2, w_down, w_up, img);
  fused_k<<<NBLK, NTH, LDSZ, stream>>>(x, topk_probs, topk_idx, b1, b2, img, out);
}

// Round 17
// 266.499 us; speedup vs baseline: 2.3304x; 1.7254x over previous
//
#include <hip/hip_runtime.h>
#include <hip/hip_bf16.h>

typedef __attribute__((ext_vector_type(4))) float float4v;
typedef __attribute__((ext_vector_type(8))) __bf16 bf16x8;
typedef __attribute__((ext_vector_type(8))) unsigned short ushort8v;

constexpr int NTOK = 50176;
constexpr int DIM  = 384;
constexpr int HID  = 1536;
constexpr int BM   = 64;          // tokens/block
constexpr int NTH  = 512;
constexpr int NBLK = NTOK / BM;   // 784
constexpr int CHW  = 32;          // hidden chunk width
constexpr int NCH  = HID / CHW;   // 48

// workspace (byte offsets) — image formats IDENTICAL to R12 (proven)
// W1-type [32 f][384 d]: 768B rows, pre-swizzled ^(f&7)<<4 — staged into LDS (x4 reuse)
// W2-type [384 d][32 k]: plain linear — B-frags read directly from global/L2 (x2 reuse)
constexpr int IMG_WD  = 0;                      // W1-type [32][384]
constexpr int IMG_WUP = 24576;                  // linear  [384][32]
constexpr int IMG_W1  = 49152;                  // 48 x W1-type
constexpr int IMG_W2  = 49152 + 48 * 12288 * 2; // 48 x linear
constexpr size_t WS_NEED = 2408448;
constexpr int NELEMS = 1204224;

// LDS (80 KiB/block => exactly 2 blocks/CU)
constexpr int L_X  = 0;        // 48K  X [64][384] bf16, 768B rows, swz (r&7)<<4 (persistent)
constexpr int L_W  = 49152;    // 24K  W1-chunk buffer (WD / W1c), swizzled rows
constexpr int L_HS = 73728;    // 8K   Hs double buffer: 2 x [64 tok][32 f] group-tiled
constexpr int LDSZ = 81920;

__device__ __forceinline__ unsigned short f2bf(float f) {
  __hip_bfloat16 h = __float2bfloat16(f);
  return *reinterpret_cast<unsigned short*>(&h);
}

__device__ __forceinline__ float gelu_f(float v) {
  float u = 0.7978845608f * (v + 0.044715f * v * v * v);
  float e = __expf(2.0f * u);
  float t = 1.0f - 2.0f / (e + 1.0f);
  return 0.5f * v * (1.0f + t);
}

// group-tiled byte address for [rows][32 cols] bf16: row r, 16B k-slot s
__device__ __forceinline__ int gt_addr(int r, int s) {
  return ((r >> 3) << 9) + (s << 7) + ((r & 7) << 4);
}

// ---- T14 staging (W1 only): load after barrier A, write after barrier B ----
__device__ __forceinline__ void st_load(const char* src, int tid, ushort8v st[3]) {
  #pragma unroll
  for (int j = 0; j < 3; ++j)
    st[j] = *(const ushort8v*)(src + tid * 16 + j * 8192);
}
__device__ __forceinline__ void st_wr(char* dst, int tid, const ushort8v st[3]) {
  #pragma unroll
  for (int j = 0; j < 3; ++j)
    *(ushort8v*)(dst + tid * 16 + j * 8192) = st[j];
}

// ---------------- pack kernel (identical to R12) ----------------
__global__ __launch_bounds__(256) void pack_k(
    const float* __restrict__ W1, const float* __restrict__ W2,
    const float* __restrict__ wd, const float* __restrict__ wu,
    unsigned short* __restrict__ img)
{
  int i = blockIdx.x * 256 + threadIdx.x;
  if (i >= NELEMS) return;
  if (i < 12288) {                               // WD (W1-type): [32 f][384 d] swz
    int f = i / 384; int inb = (i % 384) * 2;
    int d = (inb ^ ((f & 7) << 4)) >> 1;
    float v = (f < 24) ? wd[(f >> 3) * (DIM * 8) + d * 8 + (f & 7)] : 0.f;
    img[i] = f2bf(v);
  } else if (i < 24576) {                        // WUP linear [384 d][32 c]
    int j = i - 12288;
    int d = j / 32, c = j % 32;
    float v = (c < 24) ? wu[c * DIM + d] : 0.f;
    img[i] = f2bf(v);
  } else if (i < 24576 + 48 * 12288) {           // W1 chunks (W1-type swz)
    int j = i - 24576; int h = j / 12288; int jc = j % 12288;
    int f = jc / 384; int inb = (jc % 384) * 2;
    int d = (inb ^ ((f & 7) << 4)) >> 1;
    img[i] = f2bf(W1[d * HID + h * CHW + f]);
  } else {                                       // W2 chunks linear [384 d][32 k]
    int j = i - 24576 - 48 * 12288; int h = j / 12288; int jc = j % 12288;
    int d = jc / 32, k = jc % 32;
    img[i] = f2bf(W2[(h * CHW + k) * DIM + d]);
  }
}

// ---------------- fused MLP + MoE-LoRA ----------------
__global__ __launch_bounds__(NTH, 4) void fused_k(
    const float* __restrict__ x,
    const float* __restrict__ tp,
    const int*   __restrict__ ti,
    const float* __restrict__ b1,
    const float* __restrict__ b2,
    const unsigned short* __restrict__ img,
    float* __restrict__ out)
{
  extern __shared__ char lds[];
  const int tid = threadIdx.x, wid = tid >> 6, lane = tid & 63;
  const int lrow = lane & 15, g4 = lane >> 4;
  const int blockRow = blockIdx.x * BM;
  const char* imgc = (const char*)img;

  const int band = wid >> 1, chh = wid & 1;      // G1 grid: 4 bands x 2 col-halves
  const int wr = wid >> 2, wc = wid & 3;         // G2 grid: 2M x 4N

  ushort8v stg[3];                               // 12 regs; W1 pipeline only

  // ---- prologue: issue WD; X f32->bf16 -> L_X ----
  st_load(imgc + IMG_WD, tid, stg);
  {
    const float* xb = x + (size_t)blockRow * DIM;
    #pragma unroll
    for (int it = 0; it < 6; ++it) {
      int idx = it * NTH + tid;
      int row = idx / 48, c8 = idx % 48;
      float4v v0 = *(const float4v*)(xb + row * DIM + c8 * 8);
      float4v v1 = *(const float4v*)(xb + row * DIM + c8 * 8 + 4);
      ushort8v u;
      u[0]=f2bf(v0[0]); u[1]=f2bf(v0[1]); u[2]=f2bf(v0[2]); u[3]=f2bf(v0[3]);
      u[4]=f2bf(v1[0]); u[5]=f2bf(v1[1]); u[6]=f2bf(v1[2]); u[7]=f2bf(v1[3]);
      int byte = (row * 768 + c8 * 16) ^ ((row & 7) << 4);
      *(ushort8v*)(lds + L_X + byte) = u;
    }
  }
  st_wr(lds + L_W, tid, stg);                    // WD -> L_W (reg-dep waits; hidden by X stage)
  st_load(imgc + IMG_W1, tid, stg);              // W1[0]; lands under G1-moe
  __syncthreads();                               // X + WD visible

  // ---- G1-moe: t1 = X @ WdT -> [64][32]; prob*gelu -> Hs[0] ----
  {
    float4v hv = {};
    int raX = band * 16 + lrow, sA = (raX & 7) << 4, baX = raX * 768 + g4 * 16;
    int rbW = chh * 16 + lrow, sB = (rbW & 7) << 4, baW = rbW * 768 + g4 * 16;
    #pragma unroll
    for (int ks = 0; ks < 12; ++ks) {
      bf16x8 a = *(const bf16x8*)(lds + L_X + ((baX + ks * 64) ^ sA));
      bf16x8 b = *(const bf16x8*)(lds + L_W + ((baW + ks * 64) ^ sB));
      hv = __builtin_amdgcn_mfma_f32_16x16x32_bf16(a, b, hv, 0, 0, 0);
    }
    int colc = chh * 16 + lrow; int e = colc >> 3;
    #pragma unroll
    for (int r = 0; r < 4; ++r) {
      int row = band * 16 + g4 * 4 + r;
      int token = blockRow + row;
      float p = 0.f;
      if (e < 3) {
        int i0 = ti[token * 2], i1 = ti[token * 2 + 1];
        if (i0 == e) p += tp[token * 2];
        if (i1 == e) p += tp[token * 2 + 1];
      }
      float gv = p * gelu_f(hv[r]);
      int byte = gt_addr(row, colc >> 3) + ((colc & 7) << 1);
      *(unsigned short*)(lds + L_HS + byte) = f2bf(gv);
    }
  }
  __syncthreads();                               // bB-moe: Hs[0] visible; WD readers done
  st_wr(lds + L_W, tid, stg);                    // W1[0] -> L_W

  // ---- G2-moe: acc = Hs[0] @ WupT (K=32); B direct from global WUP (batched) ----
  float4v acc[2][6] = {};
  {
    bf16x8 bfr[6];
    #pragma unroll
    for (int nt = 0; nt < 6; ++nt) {
      int rd = wc * 96 + nt * 16 + lrow;
      bfr[nt] = *(const bf16x8*)(imgc + IMG_WUP + rd * 64 + g4 * 16);
    }
    bf16x8 A[2];
    #pragma unroll
    for (int mt = 0; mt < 2; ++mt) {
      int ra = wr * 32 + mt * 16 + lrow;
      A[mt] = *(const bf16x8*)(lds + L_HS + gt_addr(ra, g4));
    }
    #pragma unroll
    for (int nt = 0; nt < 6; ++nt) {
      acc[0][nt] = __builtin_amdgcn_mfma_f32_16x16x32_bf16(A[0], bfr[nt], acc[0][nt], 0, 0, 0);
      acc[1][nt] = __builtin_amdgcn_mfma_f32_16x16x32_bf16(A[1], bfr[nt], acc[1][nt], 0, 0, 0);
    }
  }

  // ---- main loop: 48 chunks, 2 barriers/chunk; W1 LDS-staged, W2 direct-global ----
  for (int h = 0; h < NCH; ++h) {
    const int hb = 4096 - ((h & 1) << 12);       // G1[h] writes Hs[1-(h&1)]
    __syncthreads();                             // bA: W1[h] visible; Hs[target] readers done
    if (h < NCH - 1)
      st_load(imgc + IMG_W1 + (h + 1) * 24576, tid, stg);  // lands under G1

    // b1 issued at phase start (used only after the MFMA chain)
    float bb = b1[h * CHW + chh * 16 + lrow];

    // G1: H = X @ W1c -> [64][32]
    float4v hv = {};
    {
      int raX = band * 16 + lrow, sA = (raX & 7) << 4, baX = raX * 768 + g4 * 16;
      int rbW = chh * 16 + lrow, sB = (rbW & 7) << 4, baW = rbW * 768 + g4 * 16;
      #pragma unroll
      for (int ks = 0; ks < 12; ++ks) {
        bf16x8 a = *(const bf16x8*)(lds + L_X + ((baX + ks * 64) ^ sA));
        bf16x8 b = *(const bf16x8*)(lds + L_W + ((baW + ks * 64) ^ sB));
        hv = __builtin_amdgcn_mfma_f32_16x16x32_bf16(a, b, hv, 0, 0, 0);
      }
    }
    // bias + gelu -> Hs[target] (group-tiled)
    {
      int colc = chh * 16 + lrow;
      #pragma unroll
      for (int r = 0; r < 4; ++r) {
        int row = band * 16 + g4 * 4 + r;
        float gv = gelu_f(hv[r] + bb);
        int byte = gt_addr(row, colc >> 3) + ((colc & 7) << 1);
        *(unsigned short*)(lds + L_HS + hb + byte) = f2bf(gv);
      }
    }
    __syncthreads();                             // bB: Hs[target] visible; G1 done with L_W
    if (h < NCH - 1)
      st_wr(lds + L_W, tid, stg);                // W1[h+1] -> L_W

    // G2: acc += Hs @ W2c (K=32); B loads batched upfront (one L2 round-trip)
    {
      const char* w2b = imgc + IMG_W2 + h * 24576;
      bf16x8 bfr[6];
      #pragma unroll
      for (int nt = 0; nt < 6; ++nt) {
        int rd = wc * 96 + nt * 16 + lrow;
        bfr[nt] = *(const bf16x8*)(w2b + rd * 64 + g4 * 16);
      }
      bf16x8 A[2];
      #pragma unroll
      for (int mt = 0; mt < 2; ++mt) {
        int ra = wr * 32 + mt * 16 + lrow;
        A[mt] = *(const bf16x8*)(lds + L_HS + hb + gt_addr(ra, g4));
      }
      #pragma unroll
      for (int nt = 0; nt < 6; ++nt) {
        acc[0][nt] = __builtin_amdgcn_mfma_f32_16x16x32_bf16(A[0], bfr[nt], acc[0][nt], 0, 0, 0);
        acc[1][nt] = __builtin_amdgcn_mfma_f32_16x16x32_bf16(A[1], bfr[nt], acc[1][nt], 0, 0, 0);
      }
    }
  }

  // ---- epilogue: + b2, store f32 ----
  #pragma unroll
  for (int nt = 0; nt < 6; ++nt) {
    int col = wc * 96 + nt * 16 + lrow;
    float bb = b2[col];
    #pragma unroll
    for (int mt = 0; mt < 2; ++mt) {
      #pragma unroll
      for (int r = 0; r < 4; ++r) {
        int row = wr * 32 + mt * 16 + g4 * 4 + r;
        out[(size_t)(blockRow + row) * DIM + col] = acc[mt][nt][r] + bb;
      }
    }
  }
}

extern "C" void kernel_launch(void* const* d_in, const int* in_sizes, int n_in,
                              void* d_out, int out_size, void* d_ws, size_t ws_size,
                              hipStream_t stream) {
  const float* x          = (const float*)d_in[0];
  const float* topk_probs = (const float*)d_in[2];
  const int*   topk_idx   = (const int*)  d_in[3];
  const float* w_down     = (const float*)d_in[4];
  const float* w_up       = (const float*)d_in[5];
  const float* W1         = (const float*)d_in[6];
  const float* b1         = (const float*)d_in[7];
  const float* W2         = (const float*)d_in[8];
  const float* b2         = (const float*)d_in[9];
  float* out = (float*)d_out;

  if (ws_size < WS_NEED) return;

  hipFuncSetAttribute(reinterpret_cast<const void*>(fused_k),
                      hipFuncAttributeMaxDynamicSharedMemorySize, LDSZ);

  unsigned short* img = (unsigned short*)d_ws;
  pack_k<<<(NELEMS + 255) / 256, 256, 0, stream>>>(W1, W2, w_down, w_up, img);
  fused_k<<<NBLK, NTH, LDSZ, stream>>>(x, topk_probs, topk_idx, b1, b2, img, out);
}